// Round 1
// baseline (2484.073 us; speedup 1.0000x reference)
//
#include <hip/hip_runtime.h>

#define B_ 16
#define N_ 1024
#define M_ 4096
#define D_ 64
#define ROWS_PER_CHUNK 256
#define NCHUNK 4
#define DP_T 256
#define DP_E 16   // elements (columns) per DP thread; DP_T*DP_E == M_

__device__ __forceinline__ float finf() { return __builtin_inff(); }

// ---------------------------------------------------------------------------
// prep: x2[b,i] = sum_k x[b,i,k]^2 ; and copy x_t -> w_ts output
// ---------------------------------------------------------------------------
__global__ void prep_kernel(const float* __restrict__ x,
                            const float* __restrict__ x_t,
                            float* __restrict__ x2,
                            float* __restrict__ w_ts_out) {
  int id = blockIdx.x * blockDim.x + threadIdx.x;  // 0 .. B_*N_-1
  const float4* xr = (const float4*)(x + (size_t)id * D_);
  float s = 0.f;
#pragma unroll
  for (int e = 0; e < D_ / 4; ++e) {
    float4 v = xr[e];
    s += v.x * v.x + v.y * v.y + v.z * v.z + v.w * v.w;
  }
  x2[id] = s;
  w_ts_out[id] = x_t[id];
}

// ---------------------------------------------------------------------------
// GEMM-ish: C[b, i-r0, j] = x2[b,i] + y2[b,j] - 2 * dot(x[b,i,:], y[b,j,:])
// One wave handles a 64-column strip; each lane caches its y row (64 floats)
// in VGPRs; x row is a lane-uniform (broadcast) load per i.
// ---------------------------------------------------------------------------
__global__ __launch_bounds__(256) void gemm_kernel(
    const float* __restrict__ x, const float* __restrict__ y,
    const float* __restrict__ x2, float* __restrict__ C,
    int r0, int rowsPerBlock, int rowsC) {
  const int b = blockIdx.z;
  const int lane = threadIdx.x & 63;
  const int wid = threadIdx.x >> 6;
  const int j = (blockIdx.x * 4 + wid) * 64 + lane;

  const float4* yrow = (const float4*)(y + ((size_t)b * M_ + j) * D_);
  float4 yr[D_ / 4];
#pragma unroll
  for (int e = 0; e < D_ / 4; ++e) yr[e] = yrow[e];
  float y2 = 0.f;
#pragma unroll
  for (int e = 0; e < D_ / 4; ++e)
    y2 += yr[e].x * yr[e].x + yr[e].y * yr[e].y + yr[e].z * yr[e].z + yr[e].w * yr[e].w;

  const int ibeg = r0 + blockIdx.y * rowsPerBlock;
  for (int i = ibeg; i < ibeg + rowsPerBlock; ++i) {
    const float4* xr = (const float4*)(x + ((size_t)b * N_ + i) * D_);
    float acc = 0.f;
#pragma unroll
    for (int e = 0; e < D_ / 4; ++e) {
      float4 xv = xr[e];
      acc += xv.x * yr[e].x + xv.y * yr[e].y + xv.z * yr[e].z + xv.w * yr[e].w;
    }
    const float cv = x2[b * N_ + i] + y2 - 2.f * acc;
    C[((size_t)b * rowsC + (i - r0)) * M_ + j] = cv;
  }
}

// ---------------------------------------------------------------------------
// DP over one row-chunk. One workgroup per batch. Row recurrence
//   D[j] = min(a[j], D[j-1] + C[j]),  a[j] = min(Dprev[j], Dprev[j-1]) + C[j]
// is a pair-scan with op (A,B)∘(A',B') = (min(A', A+B'), B+B').
// Emits 2-bit backtrack decisions (0=diag,1=up,2=left) packed 16/u32.
// Last global row: (min, first-argmin) reduction -> cost + j0.
// ---------------------------------------------------------------------------
__global__ __launch_bounds__(DP_T) void dtw_dp_kernel(
    const float* __restrict__ C, unsigned int* __restrict__ dec,
    float* __restrict__ carry, float* __restrict__ cost_out,
    int* __restrict__ j0_out, int r0, int rows) {
  const int b = blockIdx.x;
  const int t = threadIdx.x;
  const int lane = t & 63;
  const int wid = t >> 6;
  const int jbase = t * DP_E;

  __shared__ float dlast[DP_T];
  __shared__ float wpA[DP_T / 64];
  __shared__ float wpB[DP_T / 64];
  __shared__ float redV[DP_T / 64];
  __shared__ int redJ[DP_T / 64];

  const float* Cb = C + (size_t)b * rows * M_;
  unsigned int* decb = dec + (size_t)b * N_ * (M_ / DP_E);
  float* carryb = carry + b * M_;

  float dp[DP_E];
  if (r0 > 0) {
#pragma unroll
    for (int e = 0; e < DP_E / 4; ++e) {
      float4 v = ((const float4*)(carryb + jbase))[e];
      dp[4 * e] = v.x; dp[4 * e + 1] = v.y; dp[4 * e + 2] = v.z; dp[4 * e + 3] = v.w;
    }
    dlast[t] = dp[DP_E - 1];
  }
  __syncthreads();

  float cc[DP_E];
#pragma unroll
  for (int e = 0; e < DP_E / 4; ++e) {
    float4 v = ((const float4*)(Cb + jbase))[e];
    cc[4 * e] = v.x; cc[4 * e + 1] = v.y; cc[4 * e + 2] = v.z; cc[4 * e + 3] = v.w;
  }

  for (int li = 0; li < rows; ++li) {
    const int gi = r0 + li;
    // prefetch next row (clamped; harmless duplicate on last iteration)
    float cn[DP_E];
    {
      const int ln = (li + 1 < rows) ? (li + 1) : (rows - 1);
      const float* p = Cb + (size_t)ln * M_ + jbase;
#pragma unroll
      for (int e = 0; e < DP_E / 4; ++e) {
        float4 v = ((const float4*)p)[e];
        cn[4 * e] = v.x; cn[4 * e + 1] = v.y; cn[4 * e + 2] = v.z; cn[4 * e + 3] = v.w;
      }
    }

    if (gi == 0) {
      // free start: D[0,:] = C[0,:]
#pragma unroll
      for (int k = 0; k < DP_E; ++k) dp[k] = cc[k];
      dlast[t] = dp[DP_E - 1];
      __syncthreads();
    } else {
      const float dm1 = (t > 0) ? dlast[t - 1] : finf();  // Dprev[jbase-1]
      float a[DP_E];
      a[0] = fminf(dp[0], dm1) + cc[0];
#pragma unroll
      for (int k = 1; k < DP_E; ++k) a[k] = fminf(dp[k], dp[k - 1]) + cc[k];

      // serial in-thread pair scan, keeping per-element prefixes
      float pA[DP_E], pB[DP_E];
      {
        float A = a[0], Bs = cc[0];
        pA[0] = A; pB[0] = Bs;
#pragma unroll
        for (int k = 1; k < DP_E; ++k) {
          A = fminf(a[k], A + cc[k]);
          Bs = Bs + cc[k];
          pA[k] = A; pB[k] = Bs;
        }
      }
      // wave-level inclusive scan of thread totals
      float A = pA[DP_E - 1], Bs = pB[DP_E - 1];
#pragma unroll
      for (int off = 1; off < 64; off <<= 1) {
        float Au = __shfl_up(A, off);
        float Bu = __shfl_up(Bs, off);
        if (lane >= off) { A = fminf(A, Au + Bs); Bs = Bu + Bs; }
      }
      // lane-exclusive prefix within wave
      float exA = __shfl_up(A, 1);
      float exB = __shfl_up(Bs, 1);
      if (lane == 0) { exA = finf(); exB = 0.f; }
      if (lane == 63) { wpA[wid] = A; wpB[wid] = Bs; }
      __syncthreads();
      // fold earlier waves' totals (left-to-right)
      float accA = finf(), accB = 0.f;
      for (int w = 0; w < wid; ++w) {
        const float wa = wpA[w], wb = wpB[w];
        accA = fminf(wa, accA + wb);
        accB = accB + wb;
      }
      const float fExA = fminf(exA, accA + exB);  // == D[i, jbase-1]
      float Dv[DP_E];
#pragma unroll
      for (int k = 0; k < DP_E; ++k) Dv[k] = fminf(pA[k], fExA + pB[k]);

      // decisions (reference predicate order: diag wins ties, then up, then left)
      unsigned int code = 0;
      float dleft = fExA;
#pragma unroll
      for (int k = 0; k < DP_E; ++k) {
        const float dd = (k == 0) ? dm1 : dp[k - 1];
        const float du = dp[k];
        const float best = fminf(dd, fminf(du, dleft));
        const unsigned int ck = (dd == best) ? 0u : ((du == best) ? 1u : 2u);
        code |= ck << (2 * k);
        dleft = Dv[k];
      }
      decb[(size_t)gi * (M_ / DP_E) + t] = code;

#pragma unroll
      for (int k = 0; k < DP_E; ++k) dp[k] = Dv[k];
      dlast[t] = dp[DP_E - 1];
      __syncthreads();

      if (gi == N_ - 1) {
        // (min, first index) over last row
        float mv = finf(); int mj = 0;
#pragma unroll
        for (int k = 0; k < DP_E; ++k) {
          if (Dv[k] < mv) { mv = Dv[k]; mj = jbase + k; }
        }
#pragma unroll
        for (int off = 32; off > 0; off >>= 1) {
          const float ov = __shfl_down(mv, off);
          const int oj = __shfl_down(mj, off);
          if (ov < mv || (ov == mv && oj < mj)) { mv = ov; mj = oj; }
        }
        if (lane == 0) { redV[wid] = mv; redJ[wid] = mj; }
        __syncthreads();
        if (t == 0) {
#pragma unroll
          for (int w = 1; w < DP_T / 64; ++w) {
            if (redV[w] < mv || (redV[w] == mv && redJ[w] < mj)) { mv = redV[w]; mj = redJ[w]; }
          }
          cost_out[b] = mv;
          j0_out[b] = mj;
        }
      }
    }
#pragma unroll
    for (int k = 0; k < DP_E; ++k) cc[k] = cn[k];
  }

  // carry last computed row to the next chunk
#pragma unroll
  for (int e = 0; e < DP_E / 4; ++e) {
    float4 v;
    v.x = dp[4 * e]; v.y = dp[4 * e + 1]; v.z = dp[4 * e + 2]; v.w = dp[4 * e + 3];
    ((float4*)(carryb + jbase))[e] = v;
  }
}

// ---------------------------------------------------------------------------
// Backtrack along packed decisions. One block per batch, thread 0 walks.
// yl[i] = entry column of backward walk into row i; w_vs[b,i] = y_t[b, yl[i]].
// ---------------------------------------------------------------------------
__global__ void backtrack_kernel(const unsigned int* __restrict__ dec,
                                 const int* __restrict__ j0,
                                 const float* __restrict__ y_t,
                                 float* __restrict__ w_vs) {
  const int b = blockIdx.x;
  if (threadIdx.x != 0) return;
  const unsigned int* db = dec + (size_t)b * N_ * (M_ / DP_E);
  const float* yt = y_t + b * M_;
  float* wv = w_vs + b * N_;

  int j = j0[b];
  wv[N_ - 1] = yt[j];
  for (int i = N_ - 1; i >= 1; --i) {
    const unsigned int* dr = db + (size_t)i * (M_ / DP_E);
    int code;
    for (;;) {
      const int jw = j >> 4;
      unsigned long long win = dr[jw];
      int base;
      if (jw > 0) {
        win = (win << 32) | (unsigned long long)dr[jw - 1];
        base = (jw - 1) * 16;
      } else {
        base = 0;
      }
      int pos = j - base;
      bool reload = false;
      for (;;) {
        code = (int)((win >> (2 * pos)) & 3ull);
        if (code != 2) break;      // not a left-move: leave row
        --j; --pos;                 // left move
        if (pos < 0) { reload = true; break; }
      }
      if (!reload) break;
    }
    if (code == 0) --j;  // diag consumes a column
    wv[i - 1] = yt[j];   // entry column of row i-1
  }
}

// ---------------------------------------------------------------------------
extern "C" void kernel_launch(void* const* d_in, const int* in_sizes, int n_in,
                              void* d_out, int out_size, void* d_ws, size_t ws_size,
                              hipStream_t stream) {
  const float* x = (const float*)d_in[0];
  const float* y = (const float*)d_in[1];
  const float* x_t = (const float*)d_in[2];
  const float* y_t = (const float*)d_in[3];

  float* out_cost = (float*)d_out;        // [B_]
  float* out_wts = out_cost + B_;         // [B_][N_]
  float* out_wvs = out_wts + B_ * N_;     // [B_][N_]

  char* ws = (char*)d_ws;
  const size_t C_BYTES = (size_t)B_ * ROWS_PER_CHUNK * M_ * sizeof(float);       // 64 MiB
  const size_t DEC_BYTES = (size_t)B_ * N_ * (M_ / DP_E) * sizeof(unsigned int); // 16 MiB
  float* Cbuf = (float*)ws;
  unsigned int* dec = (unsigned int*)(ws + C_BYTES);
  float* x2 = (float*)(ws + C_BYTES + DEC_BYTES);
  float* carry = (float*)(ws + C_BYTES + DEC_BYTES + (size_t)B_ * N_ * sizeof(float));
  int* j0 = (int*)(ws + C_BYTES + DEC_BYTES + (size_t)B_ * N_ * sizeof(float) +
                   (size_t)B_ * M_ * sizeof(float));

  prep_kernel<<<dim3((B_ * N_) / 256), 256, 0, stream>>>(x, x_t, x2, out_wts);

  for (int c = 0; c < NCHUNK; ++c) {
    const int r0 = c * ROWS_PER_CHUNK;
    gemm_kernel<<<dim3(M_ / 256, ROWS_PER_CHUNK / 128, B_), 256, 0, stream>>>(
        x, y, x2, Cbuf, r0, 128, ROWS_PER_CHUNK);
    dtw_dp_kernel<<<dim3(B_), DP_T, 0, stream>>>(Cbuf, dec, carry, out_cost, j0,
                                                 r0, ROWS_PER_CHUNK);
  }

  backtrack_kernel<<<dim3(B_), 64, 0, stream>>>(dec, j0, y_t, out_wvs);
}

// Round 2
// 2323.795 us; speedup vs baseline: 1.0690x; 1.0690x over previous
//
#include <hip/hip_runtime.h>

#define B_ 16
#define N_ 1024
#define M_ 4096
#define D_ 64
#define ROWS_PER_CHUNK 256
#define NCHUNK 4
#define DP_NW 4                 // waves per batch (column tiles)
#define DP_T (DP_NW * 64)
#define TILE_ (M_ / DP_NW)      // 1024 cols per wave
#define DP_E (TILE_ / 64)       // 16 cells per thread
#define DP_R 8                  // edge ring depth (rows)
#define DECW_ (M_ / 16)         // dec words per row
#define BT_W 8                  // backtrack window words per lane (128 cells)

__device__ __forceinline__ float finf() { return __builtin_inff(); }

// min-plus pair-scan combine via DPP. (A,B): A = min-plus prefix value,
// B = plain sum of costs. Incoming-left (Au,Bu) combine:
//   A = min(A, Au + B); B = Bu + B.
// old = identity (INF, 0) handles both masked-out lanes (row_mask) and
// invalid-source lanes (bound_ctrl=false) -> combine is a no-op there.
template <int CTRL, int RM>
__device__ __forceinline__ void scan_step(float& A, float& B) {
  float Au = __int_as_float(__builtin_amdgcn_update_dpp(
      __float_as_int(finf()), __float_as_int(A), CTRL, RM, 0xF, false));
  float Bu = __int_as_float(__builtin_amdgcn_update_dpp(
      0, __float_as_int(B), CTRL, RM, 0xF, false));
  A = fminf(A, Au + B);
  B = Bu + B;
}

// ---------------------------------------------------------------------------
__global__ void prep_kernel(const float* __restrict__ x,
                            const float* __restrict__ x_t,
                            float* __restrict__ x2,
                            float* __restrict__ w_ts_out) {
  int id = blockIdx.x * blockDim.x + threadIdx.x;
  const float4* xr = (const float4*)(x + (size_t)id * D_);
  float s = 0.f;
#pragma unroll
  for (int e = 0; e < D_ / 4; ++e) {
    float4 v = xr[e];
    s += v.x * v.x + v.y * v.y + v.z * v.z + v.w * v.w;
  }
  x2[id] = s;
  w_ts_out[id] = x_t[id];
}

// ---------------------------------------------------------------------------
__global__ __launch_bounds__(256) void gemm_kernel(
    const float* __restrict__ x, const float* __restrict__ y,
    const float* __restrict__ x2, float* __restrict__ C,
    int r0, int rowsPerBlock, int rowsC) {
  const int b = blockIdx.z;
  const int lane = threadIdx.x & 63;
  const int wid = threadIdx.x >> 6;
  const int j = (blockIdx.x * 4 + wid) * 64 + lane;

  const float4* yrow = (const float4*)(y + ((size_t)b * M_ + j) * D_);
  float4 yr[D_ / 4];
#pragma unroll
  for (int e = 0; e < D_ / 4; ++e) yr[e] = yrow[e];
  float y2 = 0.f;
#pragma unroll
  for (int e = 0; e < D_ / 4; ++e)
    y2 += yr[e].x * yr[e].x + yr[e].y * yr[e].y + yr[e].z * yr[e].z + yr[e].w * yr[e].w;

  const int ibeg = r0 + blockIdx.y * rowsPerBlock;
  for (int i = ibeg; i < ibeg + rowsPerBlock; ++i) {
    const float4* xr = (const float4*)(x + ((size_t)b * N_ + i) * D_);
    float acc = 0.f;
#pragma unroll
    for (int e = 0; e < D_ / 4; ++e) {
      float4 xv = xr[e];
      acc += xv.x * yr[e].x + xv.y * yr[e].y + xv.z * yr[e].z + xv.w * yr[e].w;
    }
    const float cv = x2[b * N_ + i] + y2 - 2.f * acc;
    C[((size_t)b * rowsC + (i - r0)) * M_ + j] = cv;
  }
}

// ---------------------------------------------------------------------------
// DP: barrier-free skewed wave pipeline. Wave w owns cols [w*1024, w*1024+1024).
// Per row: in-thread serial min-plus scan (16 cells) -> DPP pair-scan over 64
// lanes (exclusive, via pre-shift) -> combine with left-tile edge D (LDS
// spin-published by wave w-1) -> D values + 2-bit decisions.
// ---------------------------------------------------------------------------
__global__ __launch_bounds__(DP_T) void dtw_dp_kernel(
    const float* __restrict__ C, unsigned int* __restrict__ dec,
    float* __restrict__ carry, float* __restrict__ cost_out,
    int* __restrict__ j0_out, int r0, int rows) {
  const int b = blockIdx.x;
  const int t = threadIdx.x;
  const int lane = t & 63;
  const int w = t >> 6;
  const int jbase = t * DP_E;  // == w*TILE_ + lane*DP_E

  __shared__ float eVal[DP_NW][DP_R];
  __shared__ int eTag[DP_NW][DP_R];
  __shared__ int consRow[DP_NW];
  __shared__ float redV[DP_NW];
  __shared__ int redJ[DP_NW];
  volatile float* vVal = &eVal[0][0];
  volatile int* vTag = &eTag[0][0];
  volatile int* vCons = consRow;

  if (t < DP_NW * DP_R) vTag[t] = -1;
  if (t < DP_NW) vCons[t] = r0 - 1;
  __syncthreads();

  const float* Cb = C + (size_t)b * rows * M_;
  unsigned int* decb = dec + (size_t)b * N_ * DECW_;
  float* carryb = carry + b * M_;

  float dp_[DP_E];
  float dm1 = finf();  // Dprev[jbase-1]
  if (r0 > 0) {
#pragma unroll
    for (int e = 0; e < DP_E / 4; ++e) {
      float4 v = ((const float4*)(carryb + jbase))[e];
      dp_[4 * e] = v.x; dp_[4 * e + 1] = v.y; dp_[4 * e + 2] = v.z; dp_[4 * e + 3] = v.w;
    }
    dm1 = (t > 0) ? carryb[jbase - 1] : finf();
  }

#define LOADROW(dst, LI) do { \
    const float4* _p = (const float4*)(Cb + (size_t)(LI) * M_ + jbase); \
    float4 _v0 = _p[0], _v1 = _p[1], _v2 = _p[2], _v3 = _p[3]; \
    dst[0]=_v0.x; dst[1]=_v0.y; dst[2]=_v0.z; dst[3]=_v0.w; \
    dst[4]=_v1.x; dst[5]=_v1.y; dst[6]=_v1.z; dst[7]=_v1.w; \
    dst[8]=_v2.x; dst[9]=_v2.y; dst[10]=_v2.z; dst[11]=_v2.w; \
    dst[12]=_v3.x; dst[13]=_v3.y; dst[14]=_v3.z; dst[15]=_v3.w; } while (0)

  float cur[DP_E], bufA[DP_E], bufB[DP_E];
  LOADROW(cur, 0);
  LOADROW(bufA, (1 < rows ? 1 : rows - 1));
  LOADROW(bufB, (2 < rows ? 2 : rows - 1));

  for (int li = 0; li < rows; ++li) {
    const int gi = r0 + li;
    float Dleft = finf();  // D[gi, w*TILE_-1]
    float Dv[DP_E];

    if (gi == 0) {
#pragma unroll
      for (int k = 0; k < DP_E; ++k) Dv[k] = cur[k];
      if (w > 0) {
        const int idx = (w - 1) * DP_R + (gi & (DP_R - 1));
        while (vTag[idx] != gi) {}
        Dleft = vVal[idx];
      }
    } else {
      float a[DP_E];
      a[0] = fminf(dp_[0], dm1) + cur[0];
#pragma unroll
      for (int k = 1; k < DP_E; ++k) a[k] = fminf(dp_[k], dp_[k - 1]) + cur[k];

      float pA[DP_E], pB[DP_E];
      {
        float A = a[0], Bs = cur[0];
        pA[0] = A; pB[0] = Bs;
#pragma unroll
        for (int k = 1; k < DP_E; ++k) {
          A = fminf(a[k], A + cur[k]);
          Bs = Bs + cur[k];
          pA[k] = A; pB[k] = Bs;
        }
      }
      // exclusive cross-lane pair-scan: shift totals by 1, then inclusive DPP scan
      float exA = __shfl_up(pA[DP_E - 1], 1);
      float exB = __shfl_up(pB[DP_E - 1], 1);
      if (lane == 0) { exA = finf(); exB = 0.f; }
      scan_step<0x111, 0xF>(exA, exB);  // row_shr:1
      scan_step<0x112, 0xF>(exA, exB);  // row_shr:2
      scan_step<0x114, 0xF>(exA, exB);  // row_shr:4
      scan_step<0x118, 0xF>(exA, exB);  // row_shr:8
      scan_step<0x142, 0xA>(exA, exB);  // row_bcast:15, rows 1,3
      scan_step<0x143, 0xC>(exA, exB);  // row_bcast:31, rows 2,3

      if (w > 0) {
        const int idx = (w - 1) * DP_R + (gi & (DP_R - 1));
        while (vTag[idx] != gi) {}
        Dleft = vVal[idx];
      }
      const float fExA = fminf(exA, Dleft + exB);  // D[gi, jbase-1]
#pragma unroll
      for (int k = 0; k < DP_E; ++k) Dv[k] = fminf(pA[k], fExA + pB[k]);

      unsigned int code = 0;
      float dleft = fExA;
#pragma unroll
      for (int k = 0; k < DP_E; ++k) {
        const float dd = (k == 0) ? dm1 : dp_[k - 1];
        const float du = dp_[k];
        const float best = fminf(dd, fminf(du, dleft));
        const unsigned int ck = (dd == best) ? 0u : ((du == best) ? 1u : 2u);
        code |= ck << (2 * k);
        dleft = Dv[k];
      }
      decb[(size_t)gi * DECW_ + t] = code;
    }

    if (w > 0 && lane == 0) vCons[w] = gi;  // consumed left edge for row gi

    if (w < DP_NW - 1 && lane == 63) {
      if (gi >= r0 + DP_R) {
        while (vCons[w + 1] < gi - DP_R) {}  // ring back-pressure
      }
      const int idx = w * DP_R + (gi & (DP_R - 1));
      vVal[idx] = Dv[DP_E - 1];
      __builtin_amdgcn_s_waitcnt(0xC07F);  // lgkmcnt(0) only (no vmcnt drain)
      vTag[idx] = gi;
    }

    {  // dm1 for next row: D[gi, jbase-1]
      float up = __shfl_up(Dv[DP_E - 1], 1);
      dm1 = (lane == 0) ? Dleft : up;
    }
#pragma unroll
    for (int k = 0; k < DP_E; ++k) dp_[k] = Dv[k];

    if (gi == N_ - 1) {  // (min, first-argmin) over last row
      float mv = finf(); int mj = 0;
#pragma unroll
      for (int k = 0; k < DP_E; ++k)
        if (Dv[k] < mv) { mv = Dv[k]; mj = jbase + k; }
#pragma unroll
      for (int off = 32; off > 0; off >>= 1) {
        const float ov = __shfl_down(mv, off);
        const int oj = __shfl_down(mj, off);
        if (ov < mv || (ov == mv && oj < mj)) { mv = ov; mj = oj; }
      }
      if (lane == 0) { redV[w] = mv; redJ[w] = mj; }
    }

    if (li & 1) {
#pragma unroll
      for (int k = 0; k < DP_E; ++k) cur[k] = bufB[k];
      if (li + 3 < rows) LOADROW(bufB, li + 3);
    } else {
#pragma unroll
      for (int k = 0; k < DP_E; ++k) cur[k] = bufA[k];
      if (li + 3 < rows) LOADROW(bufA, li + 3);
    }
  }

#pragma unroll
  for (int e = 0; e < DP_E / 4; ++e) {
    float4 v;
    v.x = dp_[4 * e]; v.y = dp_[4 * e + 1]; v.z = dp_[4 * e + 2]; v.w = dp_[4 * e + 3];
    ((float4*)(carryb + jbase))[e] = v;
  }

  if (r0 + rows == N_) {
    __syncthreads();
    if (t == 0) {
      float mv = redV[0]; int mj = redJ[0];
#pragma unroll
      for (int ww = 1; ww < DP_NW; ++ww)
        if (redV[ww] < mv) { mv = redV[ww]; mj = redJ[ww]; }  // ties: smaller j
      cost_out[b] = mv;
      j0_out[b] = mj;
    }
  }
}

// ---------------------------------------------------------------------------
// Backtrack: one wave per batch. Per super-step, lane l preloads an 8-word
// (128-cell) decision window of row i-l into LDS; lane 0 walks up to 64 rows
// entirely in LDS; y_t gathers happen in parallel afterwards.
// ---------------------------------------------------------------------------
__global__ __launch_bounds__(64) void backtrack_kernel(
    const unsigned int* __restrict__ dec, const int* __restrict__ j0,
    const float* __restrict__ y_t, float* __restrict__ w_vs) {
  const int b = blockIdx.x;
  const int lane = threadIdx.x;
  __shared__ unsigned int win[64][BT_W];
  __shared__ int st_i, st_j;
  __shared__ int jrow[65];
  const unsigned int* db = dec + (size_t)b * N_ * DECW_;
  const float* yt = y_t + b * M_;
  float* wv = w_vs + b * N_;

  if (lane == 0) {
    st_i = N_ - 1;
    st_j = j0[b];
    wv[N_ - 1] = yt[st_j];
  }
  for (;;) {
    __syncthreads();
    const int i = st_i, j = st_j;
    if (i <= 0) break;
    const int jw = j >> 4;
    int wb = jw - (BT_W - 1);
    if (wb < 0) wb = 0;
    const int r = i - lane;
    if (r >= 1) {
      const unsigned int* dr = db + (size_t)r * DECW_;
#pragma unroll
      for (int k = 0; k < BT_W; ++k) win[lane][k] = dr[wb + k];
    }
    __syncthreads();
    if (lane == 0) {
      const int base = wb << 4;
      int rr = i, cj = j;
      while (rr >= 1 && (i - rr) < 64) {
        const int l = i - rr;
        bool stuck = false;
        for (;;) {
          if (cj < base) { stuck = true; break; }
          const unsigned int wd = win[l][(cj >> 4) - wb];
          const int code = (int)((wd >> (2 * (cj & 15))) & 3u);
          if (code == 2) { --cj; continue; }  // left: stay in row
          if (code == 0) --cj;                // diag consumes a column
          break;
        }
        if (stuck) break;
        --rr;
        jrow[i - rr] = cj;  // entry column of row rr
      }
      st_i = rr;
      st_j = cj;
    }
    __syncthreads();
    const int ni = st_i;
    const int cnt = i - ni;
    if (lane < cnt) wv[i - 1 - lane] = yt[jrow[lane + 1]];
  }
}

// ---------------------------------------------------------------------------
extern "C" void kernel_launch(void* const* d_in, const int* in_sizes, int n_in,
                              void* d_out, int out_size, void* d_ws, size_t ws_size,
                              hipStream_t stream) {
  const float* x = (const float*)d_in[0];
  const float* y = (const float*)d_in[1];
  const float* x_t = (const float*)d_in[2];
  const float* y_t = (const float*)d_in[3];

  float* out_cost = (float*)d_out;      // [B_]
  float* out_wts = out_cost + B_;       // [B_][N_]
  float* out_wvs = out_wts + B_ * N_;   // [B_][N_]

  char* ws = (char*)d_ws;
  const size_t C_BYTES = (size_t)B_ * ROWS_PER_CHUNK * M_ * sizeof(float);       // 64 MiB
  const size_t DEC_BYTES = (size_t)B_ * N_ * DECW_ * sizeof(unsigned int);       // 16 MiB
  float* Cbuf = (float*)ws;
  unsigned int* dec = (unsigned int*)(ws + C_BYTES);
  float* x2 = (float*)(ws + C_BYTES + DEC_BYTES);
  float* carry = (float*)(ws + C_BYTES + DEC_BYTES + (size_t)B_ * N_ * sizeof(float));
  int* j0 = (int*)(ws + C_BYTES + DEC_BYTES + (size_t)B_ * N_ * sizeof(float) +
                   (size_t)B_ * M_ * sizeof(float));

  prep_kernel<<<dim3((B_ * N_) / 256), 256, 0, stream>>>(x, x_t, x2, out_wts);

  for (int c = 0; c < NCHUNK; ++c) {
    const int r0 = c * ROWS_PER_CHUNK;
    gemm_kernel<<<dim3(M_ / 256, ROWS_PER_CHUNK / 128, B_), 256, 0, stream>>>(
        x, y, x2, Cbuf, r0, 128, ROWS_PER_CHUNK);
    dtw_dp_kernel<<<dim3(B_), DP_T, 0, stream>>>(Cbuf, dec, carry, out_cost, j0,
                                                 r0, ROWS_PER_CHUNK);
  }

  backtrack_kernel<<<dim3(B_), 64, 0, stream>>>(dec, j0, y_t, out_wvs);
}